// Round 1
// baseline (280.353 us; speedup 1.0000x reference)
//
#include <hip/hip_runtime.h>

// Problem constants (reference: N=1024, F_NODE=64, F_EDGE=32, F_IN=160)
#define NN 1024
#define FN 64
#define FE 32

typedef __bf16 bf16x8 __attribute__((ext_vector_type(8)));
typedef short  short8 __attribute__((ext_vector_type(8)));
typedef float  f32x4  __attribute__((ext_vector_type(4)));

// f32 -> bf16 bits, round-to-nearest-even
static __device__ __forceinline__ unsigned short f2b(float x){
    unsigned int u = __float_as_uint(x);
    unsigned int r = (u + 0x7fffu + ((u >> 16) & 1u)) >> 16;
    return (unsigned short)r;
}

static __device__ __forceinline__ float fast_sigmoid(float y){
    // 1/(1+exp(-y)); exp->inf handled: rcp(inf)=0
    return __builtin_amdgcn_rcpf(1.0f + __expf(-y));
}

// P1b[a,j] = sum_k H[a,k] W[k,j]        + bias[j]   (H_row part)
// P2 [b,j] = sum_k H[b,k] W[64+k,j]                 (H_col part)
// Q1b, Q2: same with W_att
__global__ void prep_nodes(const float* __restrict__ H, const float* __restrict__ W,
                           const float* __restrict__ Wa, const float* __restrict__ bias,
                           float* __restrict__ P1b, float* __restrict__ P2,
                           float* __restrict__ Q1b, float* __restrict__ Q2){
    int a = blockIdx.x, j = threadIdx.x;   // 64 threads
    __shared__ float h[FN];
    h[j] = H[a*FN + j];
    __syncthreads();
    float s1 = 0.f, s2 = 0.f, s3 = 0.f, s4 = 0.f;
    #pragma unroll
    for (int k = 0; k < FN; k++){
        float hk = h[k];
        s1 = fmaf(hk, W [k*FN + j],        s1);
        s2 = fmaf(hk, W [(FN + k)*FN + j], s2);
        s3 = fmaf(hk, Wa[k*FN + j],        s3);
        s4 = fmaf(hk, Wa[(FN + k)*FN + j], s4);
    }
    float bj = bias[j];
    P1b[a*FN + j] = s1 + bj;
    P2 [a*FN + j] = s2;
    Q1b[a*FN + j] = s3 + bj;
    Q2 [a*FN + j] = s4;
}

// Transpose edge weights W[128+k][j] -> Wt[j][k] as bf16 (j-major, k contiguous)
// so B-fragments (n = lane&15, k = quad*8..+8) are contiguous 16B loads.
__global__ void prep_wedge(const float* __restrict__ W, const float* __restrict__ Wa,
                           unsigned short* __restrict__ WtE, unsigned short* __restrict__ WtA){
    int j = threadIdx.x;   // 64 threads, 2 blocks
    const float* src = blockIdx.x ? Wa : W;
    unsigned short* dst = blockIdx.x ? WtA : WtE;
    #pragma unroll
    for (int k = 0; k < FE; k++)
        dst[j*FE + k] = f2b(src[(2*FN + k)*FN + j]);
}

// One block per output row a. 4 waves; per 64-b chunk each wave owns 16 b-rows.
// A-frag built straight from global E (f32->bf16 in registers, no LDS staging).
// mfma_f32_16x16x32_bf16: A[m=lane&15][k=quad*8+i], B[k=quad*8+i][n=lane&15],
// D col=lane&15, row=quad*4+reg  [guide §3, measured m89/m91].
__global__ __launch_bounds__(256) void mga_main(
    const float* __restrict__ A, const float* __restrict__ E,
    const float* __restrict__ P1b, const float* __restrict__ P2,
    const float* __restrict__ Q1b, const float* __restrict__ Q2,
    const unsigned short* __restrict__ WtE, const unsigned short* __restrict__ WtA,
    const float* __restrict__ bias, float* __restrict__ out)
{
    int a    = blockIdx.x;
    int tid  = threadIdx.x;
    int wave = tid >> 6, lane = tid & 63;
    int col  = lane & 15, quad = lane >> 4;

    __shared__ float arow[NN];      // A[a, :], 4 KB
    __shared__ float red[16*FN];    // cross-wave/quad reduction, 4 KB

    // stage A row (coalesced float4)
    ((float4*)arow)[tid] = ((const float4*)(A + (size_t)a*NN))[tid];

    // per-lane j-constants: j = t*16 + col
    float c1[4], d1[4], g0[4], acc[4];
    #pragma unroll
    for (int t = 0; t < 4; t++){
        int j = t*16 + col;
        c1[t] = P1b[a*FN + j];
        d1[t] = Q1b[a*FN + j];
        float bj = bias[j];
        g0[t] = fmaxf(bj, 0.f) * fast_sigmoid(bj);   // A==0 contribution
        acc[t] = 0.f;
    }

    // B-fragments: 4 j-tiles x {W, W_att}, loaded once (16B/lane each)
    bf16x8 bw[4], ba[4];
    #pragma unroll
    for (int t = 0; t < 4; t++){
        int n = t*16 + col;
        bw[t] = __builtin_bit_cast(bf16x8, *(const short8*)(WtE + n*FE + quad*8));
        ba[t] = __builtin_bit_cast(bf16x8, *(const short8*)(WtA + n*FE + quad*8));
    }

    __syncthreads();   // arow visible

    const f32x4 zero = {0.f, 0.f, 0.f, 0.f};

    for (int c = 0; c < 16; c++){
        int b0 = c*64;

        // A-frag: this lane supplies E[a, b0+wave*16+col, quad*8 .. +8]
        const float* ep = E + ((size_t)a*NN + (b0 + wave*16 + col))*FE + quad*8;
        float4 e0 = *(const float4*)(ep);
        float4 e1 = *(const float4*)(ep + 4);
        short8 afs;
        afs[0] = (short)f2b(e0.x); afs[1] = (short)f2b(e0.y);
        afs[2] = (short)f2b(e0.z); afs[3] = (short)f2b(e0.w);
        afs[4] = (short)f2b(e1.x); afs[5] = (short)f2b(e1.y);
        afs[6] = (short)f2b(e1.z); afs[7] = (short)f2b(e1.w);
        bf16x8 af = __builtin_bit_cast(bf16x8, afs);

        f32x4 pw[4], pa[4];
        #pragma unroll
        for (int t = 0; t < 4; t++){
            pw[t] = __builtin_amdgcn_mfma_f32_16x16x32_bf16(af, bw[t], zero, 0, 0, 0);
            pa[t] = __builtin_amdgcn_mfma_f32_16x16x32_bf16(af, ba[t], zero, 0, 0, 0);
        }

        // epilogue: this lane owns b-rows bbase..bbase+3 (reg dim), j = t*16+col
        int bbase = b0 + wave*16 + quad*4;
        float av[4];
        #pragma unroll
        for (int r = 0; r < 4; r++) av[r] = arow[bbase + r];

        #pragma unroll
        for (int t = 0; t < 4; t++){
            int j = t*16 + col;
            #pragma unroll
            for (int r = 0; r < 4; r++){
                float sx = pw[t][r] + c1[t] + P2[(bbase + r)*FN + j];
                float sy = pa[t][r] + d1[t] + Q2[(bbase + r)*FN + j];
                float f  = fmaxf(sx, 0.f) * fast_sigmoid(sy);
                acc[t] += (av[r] != 0.f) ? f : g0[t];
            }
        }
    }

    // reduce 4 waves x 4 quads -> out[a, :]
    #pragma unroll
    for (int t = 0; t < 4; t++)
        red[(wave*4 + quad)*FN + t*16 + col] = acc[t];
    __syncthreads();
    if (tid < FN){
        float s = 0.f;
        #pragma unroll
        for (int r = 0; r < 16; r++) s += red[r*FN + tid];
        out[a*FN + tid] = s;
    }
}

extern "C" void kernel_launch(void* const* d_in, const int* in_sizes, int n_in,
                              void* d_out, int out_size, void* d_ws, size_t ws_size,
                              hipStream_t stream) {
    const float* H    = (const float*)d_in[0];
    const float* A    = (const float*)d_in[1];
    const float* E    = (const float*)d_in[2];
    const float* W    = (const float*)d_in[3];
    const float* Wa   = (const float*)d_in[4];
    const float* bias = (const float*)d_in[5];
    float* out = (float*)d_out;

    // workspace: 4 x (1024*64) f32 + 2 x (64*32) bf16  (~1.06 MB)
    float* ws  = (float*)d_ws;
    float* P1b = ws;
    float* P2  = ws + 1*NN*FN;
    float* Q1b = ws + 2*NN*FN;
    float* Q2  = ws + 3*NN*FN;
    unsigned short* WtE = (unsigned short*)(ws + 4*NN*FN);
    unsigned short* WtA = WtE + FN*FE;

    prep_nodes<<<dim3(NN), dim3(FN), 0, stream>>>(H, W, Wa, bias, P1b, P2, Q1b, Q2);
    prep_wedge<<<dim3(2),  dim3(FN), 0, stream>>>(W, Wa, WtE, WtA);
    mga_main  <<<dim3(NN), dim3(256), 0, stream>>>(A, E, P1b, P2, Q1b, Q2, WtE, WtA, bias, out);
}

// Round 2
// 270.193 us; speedup vs baseline: 1.0376x; 1.0376x over previous
//
#include <hip/hip_runtime.h>

// N=1024, F_NODE=64, F_EDGE=32, F_IN=160.
// out[a,j] = sum_b gated(a,b,j);  gated = relu(Hp)*sigmoid(Ha)
// Hp[a,b,j] = A[a,b]*(H[a]·W[0:64,j] + H[b]·W[64:128,j] + E[a,b]·W[128:160,j]) + bias[j]
// A in {0,1}: A=0 => gated = relu(bias)*sigmoid(bias) = g0[j].
// Strategy: K=160 bf16 MFMA. H[a]-slice is m-invariant & chunk-invariant ->
// 2 upfront MFMAs (broadcast A-frag, C seeded with bias) produce the C-operand
// for the per-chunk 3-MFMA chain (H[b] 2 segs + E 1 seg). No P2/Q2 arrays,
// no scalar epilogue loads.
#define NN 1024
#define FN 64
#define FE 32
#define FIN 160

typedef __bf16 bf16x8 __attribute__((ext_vector_type(8)));
typedef short  short8 __attribute__((ext_vector_type(8)));
typedef float  f32x4  __attribute__((ext_vector_type(4)));

// f32 -> bf16 bits, round-to-nearest-even
static __device__ __forceinline__ unsigned short f2b(float x){
    unsigned int u = __float_as_uint(x);
    unsigned int r = (u + 0x7fffu + ((u >> 16) & 1u)) >> 16;
    return (unsigned short)r;
}

static __device__ __forceinline__ float fast_sigmoid(float y){
    return __builtin_amdgcn_rcpf(1.0f + __expf(-y));
}

static __device__ __forceinline__ bf16x8 ldfrag(const unsigned short* p){
    return __builtin_bit_cast(bf16x8, *(const short8*)p);
}

// blocks 0..63: H (f32) -> Hb (bf16), row-major 1024x64
// block 64: W  -> WtE[j][k] bf16 (j-major, k=0..160 contiguous)
// block 65: Wa -> WtA[j][k]
__global__ void prep(const float* __restrict__ H, const float* __restrict__ W,
                     const float* __restrict__ Wa,
                     unsigned short* __restrict__ Hb,
                     unsigned short* __restrict__ WtE,
                     unsigned short* __restrict__ WtA){
    int bid = blockIdx.x, tid = threadIdx.x;
    if (bid < 64){
        int i = (bid*256 + tid)*4;
        float4 v = *(const float4*)(H + i);
        ushort4 o;
        o.x = f2b(v.x); o.y = f2b(v.y); o.z = f2b(v.z); o.w = f2b(v.w);
        *(ushort4*)(Hb + i) = o;
    } else {
        const float* src = (bid == 64) ? W : Wa;
        unsigned short* dst = (bid == 64) ? WtE : WtA;
        for (int idx = tid; idx < FIN*FN; idx += 256){
            int k = idx >> 6, j = idx & 63;   // src[k][j]
            dst[j*FIN + k] = f2b(src[idx]);
        }
    }
}

// One block per row a; 4 waves. wave = (half<<1)|mh:
//   half -> j-tiles {2*half, 2*half+1}; mh -> b-rows [mh*32, mh*32+32) per chunk.
// mfma_f32_16x16x32_bf16: A[m=lane&15][k=quad*8+i], B[k][n=lane&15],
// D: col=lane&15, row=quad*4+reg  [measured m89/m91].
__global__ __launch_bounds__(256) void mga_main(
    const float* __restrict__ A, const float* __restrict__ E,
    const unsigned short* __restrict__ Hb,
    const unsigned short* __restrict__ WtE, const unsigned short* __restrict__ WtA,
    const float* __restrict__ bias, float* __restrict__ out)
{
    int a    = blockIdx.x;
    int tid  = threadIdx.x;
    int wave = tid >> 6, lane = tid & 63;
    int col  = lane & 15, quad = lane >> 4;
    int half = wave >> 1, mh = wave & 1;

    __shared__ float arow[NN];      // A[a,:], 4 KB
    __shared__ float red[16*FN];    // reduction, 4 KB

    ((float4*)arow)[tid] = ((const float4*)(A + (size_t)a*NN))[tid];

    // Held B-fragments: segs k=64..96, 96..128, 128..160 for 2 j-tiles x 2 mats.
    bf16x8 Bw[2][3], Ba[2][3];
    #pragma unroll
    for (int tl = 0; tl < 2; tl++){
        int n = (2*half + tl)*16 + col;
        #pragma unroll
        for (int s = 0; s < 3; s++){
            Bw[tl][s] = ldfrag(WtE + n*FIN + (s+2)*32 + quad*8);
            Ba[tl][s] = ldfrag(WtA + n*FIN + (s+2)*32 + quad*8);
        }
    }

    // Upfront: cinit[t][mat] = bias[j] + sum_{k<64} H[a,k] W[k,j], via 2 MFMAs
    // with broadcast A-frag (all m-rows identical -> all 4 D regs equal).
    bf16x8 ha0 = ldfrag(Hb + a*FN + quad*8);
    bf16x8 ha1 = ldfrag(Hb + a*FN + 32 + quad*8);
    const f32x4 zero = {0.f, 0.f, 0.f, 0.f};
    f32x4 cw[2], ca[2];
    float g0[2], acc[2];
    #pragma unroll
    for (int tl = 0; tl < 2; tl++){
        int n = (2*half + tl)*16 + col;
        float bj = bias[n];
        f32x4 cb = {bj, bj, bj, bj};
        bf16x8 b0 = ldfrag(WtE + n*FIN + quad*8);
        bf16x8 b1 = ldfrag(WtE + n*FIN + 32 + quad*8);
        cw[tl] = __builtin_amdgcn_mfma_f32_16x16x32_bf16(ha1, b1,
                 __builtin_amdgcn_mfma_f32_16x16x32_bf16(ha0, b0, cb, 0,0,0), 0,0,0);
        b0 = ldfrag(WtA + n*FIN + quad*8);
        b1 = ldfrag(WtA + n*FIN + 32 + quad*8);
        ca[tl] = __builtin_amdgcn_mfma_f32_16x16x32_bf16(ha1, b1,
                 __builtin_amdgcn_mfma_f32_16x16x32_bf16(ha0, b0, cb, 0,0,0), 0,0,0);
        g0[tl] = fmaxf(bj, 0.f) * fast_sigmoid(bj);
        acc[tl] = 0.f;
    }

    __syncthreads();   // arow visible

    for (int c = 0; c < 16; c++){
        int b0r = c*64;

        // A-frags for this wave's two 16-row m-tiles
        bf16x8 ef[2], hb0[2], hb1[2];
        #pragma unroll
        for (int mt = 0; mt < 2; mt++){
            int brow = b0r + mh*32 + mt*16 + col;
            const float* ep = E + ((size_t)a*NN + brow)*FE + quad*8;
            float4 e0 = *(const float4*)(ep);
            float4 e1 = *(const float4*)(ep + 4);
            short8 afs;
            afs[0]=(short)f2b(e0.x); afs[1]=(short)f2b(e0.y);
            afs[2]=(short)f2b(e0.z); afs[3]=(short)f2b(e0.w);
            afs[4]=(short)f2b(e1.x); afs[5]=(short)f2b(e1.y);
            afs[6]=(short)f2b(e1.z); afs[7]=(short)f2b(e1.w);
            ef[mt]  = __builtin_bit_cast(bf16x8, afs);
            hb0[mt] = ldfrag(Hb + brow*FN + quad*8);
            hb1[mt] = ldfrag(Hb + brow*FN + 32 + quad*8);
        }

        #pragma unroll
        for (int mt = 0; mt < 2; mt++){
            float4 av = *(const float4*)(arow + b0r + mh*32 + mt*16 + quad*4);
            #pragma unroll
            for (int tl = 0; tl < 2; tl++){
                f32x4 pw = __builtin_amdgcn_mfma_f32_16x16x32_bf16(ef[mt], Bw[tl][2],
                           __builtin_amdgcn_mfma_f32_16x16x32_bf16(hb1[mt], Bw[tl][1],
                           __builtin_amdgcn_mfma_f32_16x16x32_bf16(hb0[mt], Bw[tl][0],
                               cw[tl], 0,0,0), 0,0,0), 0,0,0);
                f32x4 pa = __builtin_amdgcn_mfma_f32_16x16x32_bf16(ef[mt], Ba[tl][2],
                           __builtin_amdgcn_mfma_f32_16x16x32_bf16(hb1[mt], Ba[tl][1],
                           __builtin_amdgcn_mfma_f32_16x16x32_bf16(hb0[mt], Ba[tl][0],
                               ca[tl], 0,0,0), 0,0,0), 0,0,0);
                float* avp = (float*)&av;
                #pragma unroll
                for (int r = 0; r < 4; r++){
                    float f = fmaxf(pw[r], 0.f) * fast_sigmoid(pa[r]);
                    acc[tl] += (avp[r] != 0.f) ? f : g0[tl];
                }
            }
        }
    }

    // reduce: wave covers j-half `half` with b-half `mh`; quads are partials.
    #pragma unroll
    for (int tl = 0; tl < 2; tl++)
        red[(wave*4 + quad)*FN + (2*half + tl)*16 + col] = acc[tl];
    __syncthreads();
    if (tid < FN){
        int base = (tid >= 32) ? 8 : 0;
        float s = 0.f;
        #pragma unroll
        for (int r = 0; r < 8; r++) s += red[(base + r)*FN + tid];
        out[a*FN + tid] = s;
    }
}

extern "C" void kernel_launch(void* const* d_in, const int* in_sizes, int n_in,
                              void* d_out, int out_size, void* d_ws, size_t ws_size,
                              hipStream_t stream) {
    const float* H    = (const float*)d_in[0];
    const float* A    = (const float*)d_in[1];
    const float* E    = (const float*)d_in[2];
    const float* W    = (const float*)d_in[3];
    const float* Wa   = (const float*)d_in[4];
    const float* bias = (const float*)d_in[5];
    float* out = (float*)d_out;

    unsigned short* Hb  = (unsigned short*)d_ws;          // 1024*64
    unsigned short* WtE = Hb + NN*FN;                     // 64*160
    unsigned short* WtA = WtE + FN*FIN;                   // 64*160

    prep    <<<dim3(66),   dim3(256), 0, stream>>>(H, W, Wa, Hb, WtE, WtA);
    mga_main<<<dim3(NN),   dim3(256), 0, stream>>>(A, E, Hb, WtE, WtA, bias, out);
}

// Round 3
// 260.057 us; speedup vs baseline: 1.0780x; 1.0390x over previous
//
#include <hip/hip_runtime.h>

// N=1024, F_NODE=64, F_EDGE=32, F_IN=160.
// out[a,j] = sum_b gated(a,b,j);  gated = relu(Hp)*sigmoid(Ha)
// Hp[a,b,j] = A[a,b]*(H[a]·W[0:64,j] + H[b]·W[64:128,j] + E[a,b]·W[128:160,j]) + bias[j]
// A in {0,1}: A=0 => gated = relu(bias)*sigmoid(bias) = g0[j].
// R3: 4-way b-split (grid 4096) for latency hiding + v_perm truncation pack
// of E->bf16 in the hot loop. Partials in ws, second kernel reduces.
#define NN 1024
#define FN 64
#define FE 32
#define FIN 160
#define NS 4            // b-splits per row

typedef __bf16 bf16x8 __attribute__((ext_vector_type(8)));
typedef short  short8 __attribute__((ext_vector_type(8)));
typedef float  f32x4  __attribute__((ext_vector_type(4)));

// f32 -> bf16 bits, round-to-nearest-even (prep path only)
static __device__ __forceinline__ unsigned short f2b(float x){
    unsigned int u = __float_as_uint(x);
    unsigned int r = (u + 0x7fffu + ((u >> 16) & 1u)) >> 16;
    return (unsigned short)r;
}

static __device__ __forceinline__ float fast_sigmoid(float y){
    return __builtin_amdgcn_rcpf(1.0f + __expf(-y));
}

static __device__ __forceinline__ bf16x8 ldfrag(const unsigned short* p){
    return __builtin_bit_cast(bf16x8, *(const short8*)(p));
}

// pack two f32 -> (bf16_lo, bf16_hi) by truncation: one v_perm_b32
static __device__ __forceinline__ unsigned packtrunc(float lo, float hi){
    return __builtin_amdgcn_perm(__float_as_uint(hi), __float_as_uint(lo), 0x07060302u);
}

// blocks 0..63: H (f32) -> Hb (bf16) row-major 1024x64
// block 64: W -> WtE[j][k] bf16 (j-major, k contiguous); block 65: Wa -> WtA
__global__ void prep(const float* __restrict__ H, const float* __restrict__ W,
                     const float* __restrict__ Wa,
                     unsigned short* __restrict__ Hb,
                     unsigned short* __restrict__ WtE,
                     unsigned short* __restrict__ WtA){
    int bid = blockIdx.x, tid = threadIdx.x;
    if (bid < 64){
        int i = (bid*256 + tid)*4;
        float4 v = *(const float4*)(H + i);
        ushort4 o;
        o.x = f2b(v.x); o.y = f2b(v.y); o.z = f2b(v.z); o.w = f2b(v.w);
        *(ushort4*)(Hb + i) = o;
    } else {
        const float* src = (bid == 64) ? W : Wa;
        unsigned short* dst = (bid == 64) ? WtE : WtA;
        for (int idx = tid; idx < FIN*FN; idx += 256){
            int k = idx >> 6, j = idx & 63;   // src[k][j]
            dst[j*FIN + k] = f2b(src[idx]);
        }
    }
}

// Grid 4096: bid = a*NS + s; block covers b in [s*256, s*256+256), 4 chunks of 64.
// 4 waves; wave = (half<<1)|mh: half -> j-tiles {2half,2half+1}; mh -> 32-b half.
// mfma_f32_16x16x32_bf16: A[m=lane&15][k=quad*8+i], B[k][n=lane&15],
// D: col=lane&15, row=quad*4+reg  [measured m89/m91].
__global__ __launch_bounds__(256) void mga_main(
    const float* __restrict__ A, const float* __restrict__ E,
    const unsigned short* __restrict__ Hb,
    const unsigned short* __restrict__ WtE, const unsigned short* __restrict__ WtA,
    const float* __restrict__ bias, float* __restrict__ part)
{
    int bid  = blockIdx.x;
    int a    = bid / NS, s = bid % NS;
    int tid  = threadIdx.x;
    int wave = tid >> 6, lane = tid & 63;
    int col  = lane & 15, quad = lane >> 4;
    int half = wave >> 1, mh = wave & 1;
    int bbase = s * (NN / NS);            // 256-wide b-window

    __shared__ float arow[NN/NS];         // A[a, bbase:bbase+256], 1 KB
    __shared__ float red[16*FN];          // reduction, 4 KB

    arow[tid] = A[(size_t)a*NN + bbase + tid];

    // Held B-fragments: k-segs {64..96, 96..128, 128..160} x 2 j-tiles x 2 mats
    bf16x8 Bw[2][3], Ba[2][3];
    #pragma unroll
    for (int tl = 0; tl < 2; tl++){
        int n = (2*half + tl)*16 + col;
        #pragma unroll
        for (int sg = 0; sg < 3; sg++){
            Bw[tl][sg] = ldfrag(WtE + n*FIN + (sg+2)*32 + quad*8);
            Ba[tl][sg] = ldfrag(WtA + n*FIN + (sg+2)*32 + quad*8);
        }
    }

    // Upfront: c-init = bias[j] + H[a]·W[0:64,j] via 2 MFMAs (broadcast A-frag)
    bf16x8 ha0 = ldfrag(Hb + a*FN + quad*8);
    bf16x8 ha1 = ldfrag(Hb + a*FN + 32 + quad*8);
    f32x4 cw[2], ca[2];
    float g0[2], acc[2];
    #pragma unroll
    for (int tl = 0; tl < 2; tl++){
        int n = (2*half + tl)*16 + col;
        float bj = bias[n];
        f32x4 cb = {bj, bj, bj, bj};
        bf16x8 b0 = ldfrag(WtE + n*FIN + quad*8);
        bf16x8 b1 = ldfrag(WtE + n*FIN + 32 + quad*8);
        cw[tl] = __builtin_amdgcn_mfma_f32_16x16x32_bf16(ha1, b1,
                 __builtin_amdgcn_mfma_f32_16x16x32_bf16(ha0, b0, cb, 0,0,0), 0,0,0);
        b0 = ldfrag(WtA + n*FIN + quad*8);
        b1 = ldfrag(WtA + n*FIN + 32 + quad*8);
        ca[tl] = __builtin_amdgcn_mfma_f32_16x16x32_bf16(ha1, b1,
                 __builtin_amdgcn_mfma_f32_16x16x32_bf16(ha0, b0, cb, 0,0,0), 0,0,0);
        g0[tl] = fmaxf(bj, 0.f) * fast_sigmoid(bj);
        acc[tl] = 0.f;
    }

    __syncthreads();   // arow visible

    for (int cc = 0; cc < NN/NS/64; cc++){
        int b0r = cc*64;                              // local to this split

        bf16x8 ef[2], hb0[2], hb1[2];
        #pragma unroll
        for (int mt = 0; mt < 2; mt++){
            int brow = bbase + b0r + mh*32 + mt*16 + col;
            const float* ep = E + ((size_t)a*NN + brow)*FE + quad*8;
            float4 e0 = *(const float4*)(ep);
            float4 e1 = *(const float4*)(ep + 4);
            int4 pk;
            pk.x = (int)packtrunc(e0.x, e0.y);
            pk.y = (int)packtrunc(e0.z, e0.w);
            pk.z = (int)packtrunc(e1.x, e1.y);
            pk.w = (int)packtrunc(e1.z, e1.w);
            ef[mt]  = __builtin_bit_cast(bf16x8, pk);
            hb0[mt] = ldfrag(Hb + brow*FN + quad*8);
            hb1[mt] = ldfrag(Hb + brow*FN + 32 + quad*8);
        }

        #pragma unroll
        for (int mt = 0; mt < 2; mt++){
            float4 av = *(const float4*)(arow + b0r + mh*32 + mt*16 + quad*4);
            #pragma unroll
            for (int tl = 0; tl < 2; tl++){
                f32x4 pw = __builtin_amdgcn_mfma_f32_16x16x32_bf16(ef[mt], Bw[tl][2],
                           __builtin_amdgcn_mfma_f32_16x16x32_bf16(hb1[mt], Bw[tl][1],
                           __builtin_amdgcn_mfma_f32_16x16x32_bf16(hb0[mt], Bw[tl][0],
                               cw[tl], 0,0,0), 0,0,0), 0,0,0);
                f32x4 pa = __builtin_amdgcn_mfma_f32_16x16x32_bf16(ef[mt], Ba[tl][2],
                           __builtin_amdgcn_mfma_f32_16x16x32_bf16(hb1[mt], Ba[tl][1],
                           __builtin_amdgcn_mfma_f32_16x16x32_bf16(hb0[mt], Ba[tl][0],
                               ca[tl], 0,0,0), 0,0,0), 0,0,0);
                float* avp = (float*)&av;
                #pragma unroll
                for (int r = 0; r < 4; r++){
                    float f = fmaxf(pw[r], 0.f) * fast_sigmoid(pa[r]);
                    acc[tl] += (avp[r] != 0.f) ? f : g0[tl];
                }
            }
        }
    }

    // reduce within block -> part[s][a][:]
    #pragma unroll
    for (int tl = 0; tl < 2; tl++)
        red[(wave*4 + quad)*FN + (2*half + tl)*16 + col] = acc[tl];
    __syncthreads();
    if (tid < FN){
        int base = (tid >= 32) ? 8 : 0;   // waves 0,1 hold j<32; waves 2,3 hold j>=32
        float sum = 0.f;
        #pragma unroll
        for (int r = 0; r < 8; r++) sum += red[(base + r)*FN + tid];
        part[((size_t)s*NN + a)*FN + tid] = sum;
    }
}

// out = sum_s part[s]; 65536 floats = 16384 float4
__global__ void mga_reduce(const float* __restrict__ part, float* __restrict__ out){
    int i = blockIdx.x*256 + threadIdx.x;
    float4 v = ((const float4*)part)[i];
    #pragma unroll
    for (int s = 1; s < NS; s++){
        float4 p = ((const float4*)(part + (size_t)s*NN*FN))[i];
        v.x += p.x; v.y += p.y; v.z += p.z; v.w += p.w;
    }
    ((float4*)out)[i] = v;
}

extern "C" void kernel_launch(void* const* d_in, const int* in_sizes, int n_in,
                              void* d_out, int out_size, void* d_ws, size_t ws_size,
                              hipStream_t stream) {
    const float* H    = (const float*)d_in[0];
    const float* A    = (const float*)d_in[1];
    const float* E    = (const float*)d_in[2];
    const float* W    = (const float*)d_in[3];
    const float* Wa   = (const float*)d_in[4];
    const float* bias = (const float*)d_in[5];
    float* out = (float*)d_out;

    unsigned short* Hb  = (unsigned short*)d_ws;          // 1024*64 bf16
    unsigned short* WtE = Hb + NN*FN;                     // 64*160
    unsigned short* WtA = WtE + FN*FIN;                   // 64*160
    float* part = (float*)(WtA + FN*FIN);                 // NS*1024*64 f32 (1 MB)

    prep      <<<dim3(66),      dim3(256), 0, stream>>>(H, W, Wa, Hb, WtE, WtA);
    mga_main  <<<dim3(NN*NS),   dim3(256), 0, stream>>>(A, E, Hb, WtE, WtA, bias, part);
    mga_reduce<<<dim3(64),      dim3(256), 0, stream>>>(part, out);
}

// Round 4
// 242.434 us; speedup vs baseline: 1.1564x; 1.0727x over previous
//
#include <hip/hip_runtime.h>

// N=1024, F_NODE=64, F_EDGE=32, F_IN=160.
// out[a,j] = sum_b gated(a,b,j);  gated = relu(Hp)*sigmoid(Ha)
// Hp[a,b,j] = A[a,b]*(H[a]·W[0:64,j] + H[b]·W[64:128,j] + E[a,b]·W[128:160,j]) + bias[j]
// A in {0,1}. A=0 pairs contribute the constant g0[j]=relu(bias)*sigmoid(bias):
// R4: compact A=1 column indices per row, process only those (~50%), add
// (N-cnt1)*g0 in the reduce. Chunk loop software-pipelined (register prefetch
// of next chunk's E + Hb). K=160 folded into MFMA C-chaining as before.
#define NN 1024
#define FN 64
#define FE 32
#define FIN 160
#define NS 2            // splits of the compacted list per row

typedef __bf16 bf16x8 __attribute__((ext_vector_type(8)));
typedef short  short8 __attribute__((ext_vector_type(8)));
typedef float  f32x4  __attribute__((ext_vector_type(4)));

static __device__ __forceinline__ unsigned short f2b(float x){
    unsigned int u = __float_as_uint(x);
    unsigned int r = (u + 0x7fffu + ((u >> 16) & 1u)) >> 16;
    return (unsigned short)r;
}

static __device__ __forceinline__ float fast_sigmoid(float y){
    return __builtin_amdgcn_rcpf(1.0f + __expf(-y));
}

static __device__ __forceinline__ bf16x8 ldfrag(const unsigned short* p){
    return __builtin_bit_cast(bf16x8, *(const short8*)(p));
}

// pack two f32 -> (bf16 lo, bf16 hi) by truncation: one v_perm_b32
static __device__ __forceinline__ unsigned packtrunc(float lo, float hi){
    return __builtin_amdgcn_perm(__float_as_uint(hi), __float_as_uint(lo), 0x07060302u);
}

// blocks 0..63: H f32 -> Hb bf16 (1024x64); block 64/65: W/Wa -> Wt[j][k] bf16
__global__ void prep(const float* __restrict__ H, const float* __restrict__ W,
                     const float* __restrict__ Wa,
                     unsigned short* __restrict__ Hb,
                     unsigned short* __restrict__ WtE,
                     unsigned short* __restrict__ WtA){
    int bid = blockIdx.x, tid = threadIdx.x;
    if (bid < 64){
        int i = (bid*256 + tid)*4;
        float4 v = *(const float4*)(H + i);
        ushort4 o;
        o.x = f2b(v.x); o.y = f2b(v.y); o.z = f2b(v.z); o.w = f2b(v.w);
        *(ushort4*)(Hb + i) = o;
    } else {
        const float* src = (bid == 64) ? W : Wa;
        unsigned short* dst = (bid == 64) ? WtE : WtA;
        for (int idx = tid; idx < FIN*FN; idx += 256){
            int k = idx >> 6, j = idx & 63;
            dst[j*FIN + k] = f2b(src[idx]);
        }
    }
}

// Per row a: compact b-indices with A[a,b]!=0 (order irrelevant) into idxg[a][.]
__global__ void compact(const float* __restrict__ A, unsigned short* __restrict__ idxg,
                        int* __restrict__ cnt){
    int a = blockIdx.x, tid = threadIdx.x;
    __shared__ int total;
    if (tid == 0) total = 0;
    __syncthreads();
    unsigned short mine[4]; int m = 0;
    #pragma unroll
    for (int k = 0; k < 4; k++){
        int b = k*256 + tid;
        if (A[(size_t)a*NN + b] != 0.f) mine[m++] = (unsigned short)b;
    }
    int pos = atomicAdd(&total, m);
    for (int i = 0; i < m; i++) idxg[(size_t)a*NN + pos + i] = mine[i];
    __syncthreads();
    if (tid == 0) cnt[a] = total;
}

// Grid 2048: bid = a*NS + s. Block processes a window of row a's compacted
// list in 64-entry chunks. 4 waves, wave=(half<<1)|mh: half -> j-tiles
// {2half,2half+1}, mh -> 32-entry half of the chunk.
// mfma_f32_16x16x32_bf16: A[m=lane&15][k=quad*8+i], B[k][n=lane&15],
// D: col=lane&15, row=quad*4+reg  [measured m89/m91].
__global__ __launch_bounds__(256) void mga_main(
    const float* __restrict__ E,
    const unsigned short* __restrict__ Hb,
    const unsigned short* __restrict__ WtE, const unsigned short* __restrict__ WtA,
    const unsigned short* __restrict__ idxg, const int* __restrict__ cnt,
    const float* __restrict__ bias, float* __restrict__ part)
{
    int bid  = blockIdx.x;
    int a    = bid >> 1, s = bid & 1;
    int tid  = threadIdx.x;
    int wave = tid >> 6, lane = tid & 63;
    int col  = lane & 15, quad = lane >> 4;
    int half = wave >> 1, mh = wave & 1;

    __shared__ unsigned short lidx[384];   // this block's (padded) index window
    __shared__ float red[16*FN];

    int c1   = cnt[a];
    int hlen = (c1 + 1) >> 1;
    int win  = s ? hlen : 0;
    int len  = s ? (c1 - hlen) : hlen;
    int npad = (len + 63) & ~63;

    for (int i = tid; i < npad; i += 256){
        int off = (i < len) ? i : (len - 1);
        lidx[i] = idxg[(size_t)a*NN + win + off];
    }

    // Held B-frags: k-segs {64..96,96..128,128..160} x 2 j-tiles x 2 mats
    bf16x8 Bw[2][3], Ba[2][3];
    #pragma unroll
    for (int tl = 0; tl < 2; tl++){
        int n = (2*half + tl)*16 + col;
        #pragma unroll
        for (int sg = 0; sg < 3; sg++){
            Bw[tl][sg] = ldfrag(WtE + n*FIN + (sg+2)*32 + quad*8);
            Ba[tl][sg] = ldfrag(WtA + n*FIN + (sg+2)*32 + quad*8);
        }
    }

    // Upfront c-init = bias[j] + H[a]·W[0:64,j] via broadcast-A MFMAs
    bf16x8 ha0 = ldfrag(Hb + a*FN + quad*8);
    bf16x8 ha1 = ldfrag(Hb + a*FN + 32 + quad*8);
    f32x4 cw[2], ca[2];
    float acc[2];
    #pragma unroll
    for (int tl = 0; tl < 2; tl++){
        int n = (2*half + tl)*16 + col;
        float bj = bias[n];
        f32x4 cb = {bj, bj, bj, bj};
        bf16x8 b0 = ldfrag(WtE + n*FIN + quad*8);
        bf16x8 b1 = ldfrag(WtE + n*FIN + 32 + quad*8);
        cw[tl] = __builtin_amdgcn_mfma_f32_16x16x32_bf16(ha1, b1,
                 __builtin_amdgcn_mfma_f32_16x16x32_bf16(ha0, b0, cb, 0,0,0), 0,0,0);
        b0 = ldfrag(WtA + n*FIN + quad*8);
        b1 = ldfrag(WtA + n*FIN + 32 + quad*8);
        ca[tl] = __builtin_amdgcn_mfma_f32_16x16x32_bf16(ha1, b1,
                 __builtin_amdgcn_mfma_f32_16x16x32_bf16(ha0, b0, cb, 0,0,0), 0,0,0);
        acc[tl] = 0.f;
    }

    __syncthreads();   // lidx visible

    // software-pipelined chunk loop: prefetch chunk p+64 while computing p
    float4 ce0[2], ce1[2]; bf16x8 ch0[2], ch1[2];

    auto loadchunk = [&](int p, float4* e0, float4* e1, bf16x8* h0, bf16x8* h1){
        #pragma unroll
        for (int mt = 0; mt < 2; mt++){
            int r = lidx[p + mh*32 + mt*16 + col] & (NN - 1);
            const float* ep = E + ((size_t)a*NN + r)*FE + quad*8;
            e0[mt] = *(const float4*)(ep);
            e1[mt] = *(const float4*)(ep + 4);
            h0[mt] = ldfrag(Hb + r*FN + quad*8);
            h1[mt] = ldfrag(Hb + r*FN + 32 + quad*8);
        }
    };

    if (npad > 0) loadchunk(0, ce0, ce1, ch0, ch1);

    for (int p = 0; p < npad; p += 64){
        float4 ne0[2], ne1[2]; bf16x8 nh0[2], nh1[2];
        bool more = (p + 64) < npad;
        if (more) loadchunk(p + 64, ne0, ne1, nh0, nh1);

        bool full = (p + 64) <= len;
        #pragma unroll
        for (int mt = 0; mt < 2; mt++){
            int4 pk;
            pk.x = (int)packtrunc(ce0[mt].x, ce0[mt].y);
            pk.y = (int)packtrunc(ce0[mt].z, ce0[mt].w);
            pk.z = (int)packtrunc(ce1[mt].x, ce1[mt].y);
            pk.w = (int)packtrunc(ce1[mt].z, ce1[mt].w);
            bf16x8 ef = __builtin_bit_cast(bf16x8, pk);
            #pragma unroll
            for (int tl = 0; tl < 2; tl++){
                f32x4 pw = __builtin_amdgcn_mfma_f32_16x16x32_bf16(ef, Bw[tl][2],
                           __builtin_amdgcn_mfma_f32_16x16x32_bf16(ch1[mt], Bw[tl][1],
                           __builtin_amdgcn_mfma_f32_16x16x32_bf16(ch0[mt], Bw[tl][0],
                               cw[tl], 0,0,0), 0,0,0), 0,0,0);
                f32x4 pa = __builtin_amdgcn_mfma_f32_16x16x32_bf16(ef, Ba[tl][2],
                           __builtin_amdgcn_mfma_f32_16x16x32_bf16(ch1[mt], Ba[tl][1],
                           __builtin_amdgcn_mfma_f32_16x16x32_bf16(ch0[mt], Ba[tl][0],
                               ca[tl], 0,0,0), 0,0,0), 0,0,0);
                if (full){
                    #pragma unroll
                    for (int r = 0; r < 4; r++)
                        acc[tl] += fmaxf(pw[r], 0.f) * fast_sigmoid(pa[r]);
                } else {
                    #pragma unroll
                    for (int r = 0; r < 4; r++){
                        int pos = p + mh*32 + mt*16 + quad*4 + r;
                        float f = fmaxf(pw[r], 0.f) * fast_sigmoid(pa[r]);
                        acc[tl] += (pos < len) ? f : 0.f;
                    }
                }
            }
        }

        if (more){
            #pragma unroll
            for (int mt = 0; mt < 2; mt++){
                ce0[mt] = ne0[mt]; ce1[mt] = ne1[mt];
                ch0[mt] = nh0[mt]; ch1[mt] = nh1[mt];
            }
        }
    }

    #pragma unroll
    for (int tl = 0; tl < 2; tl++)
        red[(wave*4 + quad)*FN + (2*half + tl)*16 + col] = acc[tl];
    __syncthreads();
    if (tid < FN){
        int base = (tid >= 32) ? 8 : 0;   // waves 0,1: j<32; waves 2,3: j>=32
        float sum = 0.f;
        #pragma unroll
        for (int r = 0; r < 8; r++) sum += red[(base + r)*FN + tid];
        part[((size_t)s*NN + a)*FN + tid] = sum;
    }
}

// out[a,j] = part0 + part1 + (N - cnt1[a]) * g0[j]
__global__ void mga_reduce(const float* __restrict__ part, const int* __restrict__ cnt,
                           const float* __restrict__ bias, float* __restrict__ out){
    int i = blockIdx.x*256 + threadIdx.x;   // 0..65535
    int a = i >> 6, j = i & 63;
    float bj = bias[j];
    float g0 = fmaxf(bj, 0.f) * fast_sigmoid(bj);
    float c0 = (float)(NN - cnt[a]);
    out[i] = part[i] + part[(size_t)NN*FN + i] + c0 * g0;
}

extern "C" void kernel_launch(void* const* d_in, const int* in_sizes, int n_in,
                              void* d_out, int out_size, void* d_ws, size_t ws_size,
                              hipStream_t stream) {
    const float* H    = (const float*)d_in[0];
    const float* A    = (const float*)d_in[1];
    const float* E    = (const float*)d_in[2];
    const float* W    = (const float*)d_in[3];
    const float* Wa   = (const float*)d_in[4];
    const float* bias = (const float*)d_in[5];
    float* out = (float*)d_out;

    unsigned short* Hb   = (unsigned short*)d_ws;         // 1024*64
    unsigned short* WtE  = Hb + NN*FN;                    // 64*160
    unsigned short* WtA  = WtE + FN*FIN;                  // 64*160
    unsigned short* idxg = WtA + FN*FIN;                  // 1024*1024 (2 MB)
    int*            cnt  = (int*)(idxg + (size_t)NN*NN);  // 1024
    float*          part = (float*)(cnt + NN);            // NS*1024*64 (512 KB)

    prep      <<<dim3(66),    dim3(256), 0, stream>>>(H, W, Wa, Hb, WtE, WtA);
    compact   <<<dim3(NN),    dim3(256), 0, stream>>>(A, idxg, cnt);
    mga_main  <<<dim3(NN*NS), dim3(256), 0, stream>>>(E, Hb, WtE, WtA, idxg, cnt, bias, part);
    mga_reduce<<<dim3(256),   dim3(256), 0, stream>>>(part, cnt, bias, out);
}

// Round 7
// 240.716 us; speedup vs baseline: 1.1647x; 1.0071x over previous
//
#include <hip/hip_runtime.h>

// N=1024, F_NODE=64, F_EDGE=32, F_IN=160.
// out[a,j] = sum_b gated(a,b,j);  gated = relu(Hp)*sigmoid(Ha)
// Hp[a,b,j] = A[a,b]*(H[a]·W[0:64,j] + H[b]·W[64:128,j] + E[a,b]·W[128:160,j]) + bias[j]
// A in {0,1}: A=0 pairs contribute g0[j]=relu(bias)*sigmoid(bias) (constant).
// R7: back to the R4-passing structure (per-lane register loads, compacted
// A=1 gather, NS=2). Latency fix: __launch_bounds__(256,3) grants ~168 VGPR
// so the scheduler stops sinking loads (R4 showed VGPR=60 => prefetch was
// deleted), and each iteration batches TWO 64-row chunks' loads (16x16B
// independent loads in flight) before any compute. No cross-wave LDS staging
// (R5/R6 both failed on that mechanism).
#define NN 1024
#define FN 64
#define FE 32
#define FIN 160
#define NS 2            // splits of the compacted list per row

typedef __bf16 bf16x8 __attribute__((ext_vector_type(8)));
typedef short  short8 __attribute__((ext_vector_type(8)));
typedef float  f32x4  __attribute__((ext_vector_type(4)));

static __device__ __forceinline__ unsigned short f2b(float x){
    unsigned int u = __float_as_uint(x);
    unsigned int r = (u + 0x7fffu + ((u >> 16) & 1u)) >> 16;
    return (unsigned short)r;
}

static __device__ __forceinline__ float fast_sigmoid(float y){
    return __builtin_amdgcn_rcpf(1.0f + __expf(-y));
}

static __device__ __forceinline__ bf16x8 ldfrag(const unsigned short* p){
    return __builtin_bit_cast(bf16x8, *(const short8*)(p));
}

// pack two f32 -> (bf16 lo, bf16 hi) by truncation: one v_perm_b32
static __device__ __forceinline__ unsigned packtrunc(float lo, float hi){
    return __builtin_amdgcn_perm(__float_as_uint(hi), __float_as_uint(lo), 0x07060302u);
}

// blocks 0..63: H f32 -> Hb bf16 (1024x64); block 64/65: W/Wa -> Wt[j][k] bf16
__global__ void prep(const float* __restrict__ H, const float* __restrict__ W,
                     const float* __restrict__ Wa,
                     unsigned short* __restrict__ Hb,
                     unsigned short* __restrict__ WtE,
                     unsigned short* __restrict__ WtA){
    int bid = blockIdx.x, tid = threadIdx.x;
    if (bid < 64){
        int i = (bid*256 + tid)*4;
        float4 v = *(const float4*)(H + i);
        ushort4 o;
        o.x = f2b(v.x); o.y = f2b(v.y); o.z = f2b(v.z); o.w = f2b(v.w);
        *(ushort4*)(Hb + i) = o;
    } else {
        const float* src = (bid == 64) ? W : Wa;
        unsigned short* dst = (bid == 64) ? WtE : WtA;
        for (int idx = tid; idx < FIN*FN; idx += 256){
            int k = idx >> 6, j = idx & 63;
            dst[j*FIN + k] = f2b(src[idx]);
        }
    }
}

// Per row a: compact b with A[a,b]!=0 (order irrelevant) into idxg[a][.]
__global__ void compact(const float* __restrict__ A, unsigned short* __restrict__ idxg,
                        int* __restrict__ cnt){
    int a = blockIdx.x, tid = threadIdx.x;
    __shared__ int total;
    if (tid == 0) total = 0;
    __syncthreads();
    unsigned short mine[4]; int m = 0;
    #pragma unroll
    for (int k = 0; k < 4; k++){
        int b = k*256 + tid;
        if (A[(size_t)a*NN + b] != 0.f) mine[m++] = (unsigned short)b;
    }
    int pos = atomicAdd(&total, m);
    for (int i = 0; i < m; i++) idxg[(size_t)a*NN + pos + i] = mine[i];
    __syncthreads();
    if (tid == 0) cnt[a] = total;
}

// Grid 2048: bid = a*NS + s; block processes its half of row a's compacted
// list, 128 rows (2 sub-chunks) per iteration, loads batched before compute.
// 4 waves, wave=(half<<1)|mh: half -> j-tiles {2half,2half+1}, mh -> 32-row
// half of each 64-row sub-chunk.
// mfma_f32_16x16x32_bf16: A[m=lane&15][k=quad*8+i], B[k][n=lane&15],
// D: col=lane&15, row=quad*4+reg  [measured m89/m91].
__global__ __launch_bounds__(256, 3) void mga_main(
    const float* __restrict__ E,
    const unsigned short* __restrict__ Hb,
    const unsigned short* __restrict__ WtE, const unsigned short* __restrict__ WtA,
    const unsigned short* __restrict__ idxg, const int* __restrict__ cnt,
    const float* __restrict__ bias, float* __restrict__ part)
{
    int bid  = blockIdx.x;
    int a    = bid >> 1, s = bid & 1;
    int tid  = threadIdx.x;
    int wave = tid >> 6, lane = tid & 63;
    int col  = lane & 15, quad = lane >> 4;
    int half = wave >> 1, mh = wave & 1;

    __shared__ unsigned short lidx[512];   // this block's (padded) index window
    __shared__ float red[16*FN];

    int c1   = cnt[a];
    int hlen = (c1 + 1) >> 1;
    int win  = s ? hlen : 0;
    int len  = s ? (c1 - hlen) : hlen;
    int npad = (len + 63) & ~63;

    for (int i = tid; i < npad; i += 256){
        int off = (i < len) ? i : (len - 1);
        lidx[i] = idxg[(size_t)a*NN + win + off];
    }

    // Held B-frags: k-segs {64..96,96..128,128..160} x 2 j-tiles x 2 mats
    bf16x8 Bw[2][3], Ba[2][3];
    #pragma unroll
    for (int tl = 0; tl < 2; tl++){
        int n = (2*half + tl)*16 + col;
        #pragma unroll
        for (int sg = 0; sg < 3; sg++){
            Bw[tl][sg] = ldfrag(WtE + n*FIN + (sg+2)*32 + quad*8);
            Ba[tl][sg] = ldfrag(WtA + n*FIN + (sg+2)*32 + quad*8);
        }
    }

    // Upfront c-init = bias[j] + H[a]·W[0:64,j] via broadcast-A MFMAs
    bf16x8 ha0 = ldfrag(Hb + a*FN + quad*8);
    bf16x8 ha1 = ldfrag(Hb + a*FN + 32 + quad*8);
    f32x4 cw[2], ca[2];
    float acc[2] = {0.f, 0.f};
    #pragma unroll
    for (int tl = 0; tl < 2; tl++){
        int n = (2*half + tl)*16 + col;
        float bj = bias[n];
        f32x4 cb = {bj, bj, bj, bj};
        bf16x8 b0 = ldfrag(WtE + n*FIN + quad*8);
        bf16x8 b1 = ldfrag(WtE + n*FIN + 32 + quad*8);
        cw[tl] = __builtin_amdgcn_mfma_f32_16x16x32_bf16(ha1, b1,
                 __builtin_amdgcn_mfma_f32_16x16x32_bf16(ha0, b0, cb, 0,0,0), 0,0,0);
        b0 = ldfrag(WtA + n*FIN + quad*8);
        b1 = ldfrag(WtA + n*FIN + 32 + quad*8);
        ca[tl] = __builtin_amdgcn_mfma_f32_16x16x32_bf16(ha1, b1,
                 __builtin_amdgcn_mfma_f32_16x16x32_bf16(ha0, b0, cb, 0,0,0), 0,0,0);
    }

    __syncthreads();   // lidx visible

    // In-flight data for 2 sub-chunks x 2 m-tiles (per-lane register path)
    float4 e0[2][2], e1[2][2]; bf16x8 h0[2][2], h1[2][2];

    auto loadsub = [&](int p, int sub){
        #pragma unroll
        for (int mt = 0; mt < 2; mt++){
            int r = lidx[p + mh*32 + mt*16 + col] & (NN - 1);
            const float* ep = E + ((size_t)a*NN + r)*FE + quad*8;
            e0[sub][mt] = *(const float4*)(ep);
            e1[sub][mt] = *(const float4*)(ep + 4);
            h0[sub][mt] = ldfrag(Hb + r*FN + quad*8);
            h1[sub][mt] = ldfrag(Hb + r*FN + 32 + quad*8);
        }
    };

    auto compsub = [&](int p, int sub){
        bool full = (p + 64) <= len;
        #pragma unroll
        for (int mt = 0; mt < 2; mt++){
            int4 pk;
            pk.x = (int)packtrunc(e0[sub][mt].x, e0[sub][mt].y);
            pk.y = (int)packtrunc(e0[sub][mt].z, e0[sub][mt].w);
            pk.z = (int)packtrunc(e1[sub][mt].x, e1[sub][mt].y);
            pk.w = (int)packtrunc(e1[sub][mt].z, e1[sub][mt].w);
            bf16x8 ef = __builtin_bit_cast(bf16x8, pk);
            #pragma unroll
            for (int tl = 0; tl < 2; tl++){
                f32x4 pw = __builtin_amdgcn_mfma_f32_16x16x32_bf16(ef, Bw[tl][2],
                           __builtin_amdgcn_mfma_f32_16x16x32_bf16(h1[sub][mt], Bw[tl][1],
                           __builtin_amdgcn_mfma_f32_16x16x32_bf16(h0[sub][mt], Bw[tl][0],
                               cw[tl], 0,0,0), 0,0,0), 0,0,0);
                f32x4 pa = __builtin_amdgcn_mfma_f32_16x16x32_bf16(ef, Ba[tl][2],
                           __builtin_amdgcn_mfma_f32_16x16x32_bf16(h1[sub][mt], Ba[tl][1],
                           __builtin_amdgcn_mfma_f32_16x16x32_bf16(h0[sub][mt], Ba[tl][0],
                               ca[tl], 0,0,0), 0,0,0), 0,0,0);
                if (full){
                    #pragma unroll
                    for (int r = 0; r < 4; r++)
                        acc[tl] += fmaxf(pw[r], 0.f) * fast_sigmoid(pa[r]);
                } else {
                    #pragma unroll
                    for (int r = 0; r < 4; r++){
                        int pos = p + mh*32 + mt*16 + quad*4 + r;
                        float f = fmaxf(pw[r], 0.f) * fast_sigmoid(pa[r]);
                        acc[tl] += (pos < len) ? f : 0.f;
                    }
                }
            }
        }
    };

    for (int p = 0; p < npad; p += 128){
        bool hasB = (p + 64) < npad;          // uniform per block
        loadsub(p, 0);
        if (hasB) loadsub(p + 64, 1);         // 16 independent loads in flight
        compsub(p, 0);
        if (hasB) compsub(p + 64, 1);
    }

    #pragma unroll
    for (int tl = 0; tl < 2; tl++)
        red[(wave*4 + quad)*FN + (2*half + tl)*16 + col] = acc[tl];
    __syncthreads();
    if (tid < FN){
        int base = (tid >= 32) ? 8 : 0;   // waves 0,1: j<32; waves 2,3: j>=32
        float sum = 0.f;
        #pragma unroll
        for (int r = 0; r < 8; r++) sum += red[(base + r)*FN + tid];
        part[((size_t)s*NN + a)*FN + tid] = sum;
    }
}

// out[a,j] = part0 + part1 + (N - cnt1[a]) * g0[j]
__global__ void mga_reduce(const float* __restrict__ part, const int* __restrict__ cnt,
                           const float* __restrict__ bias, float* __restrict__ out){
    int i = blockIdx.x*256 + threadIdx.x;   // 0..65535
    int a = i >> 6, j = i & 63;
    float bj = bias[j];
    float g0 = fmaxf(bj, 0.f) * fast_sigmoid(bj);
    float c0 = (float)(NN - cnt[a]);
    out[i] = part[i] + part[(size_t)NN*FN + i] + c0 * g0;
}

extern "C" void kernel_launch(void* const* d_in, const int* in_sizes, int n_in,
                              void* d_out, int out_size, void* d_ws, size_t ws_size,
                              hipStream_t stream) {
    const float* H    = (const float*)d_in[0];
    const float* A    = (const float*)d_in[1];
    const float* E    = (const float*)d_in[2];
    const float* W    = (const float*)d_in[3];
    const float* Wa   = (const float*)d_in[4];
    const float* bias = (const float*)d_in[5];
    float* out = (float*)d_out;

    unsigned short* Hb   = (unsigned short*)d_ws;         // 1024*64 bf16
    unsigned short* WtE  = Hb + NN*FN;                    // 64*160
    unsigned short* WtA  = WtE + FN*FIN;                  // 64*160
    unsigned short* idxg = WtA + FN*FIN;                  // 1024*1024 u16 (2 MB)
    int*            cnt  = (int*)(idxg + (size_t)NN*NN);  // 1024
    float*          part = (float*)(cnt + NN);            // NS*1024*64 f32

    prep      <<<dim3(66),    dim3(256), 0, stream>>>(H, W, Wa, Hb, WtE, WtA);
    compact   <<<dim3(NN),    dim3(256), 0, stream>>>(A, idxg, cnt);
    mga_main  <<<dim3(NN*NS), dim3(256), 0, stream>>>(E, Hb, WtE, WtA, idxg, cnt, bias, part);
    mga_reduce<<<dim3(256),   dim3(256), 0, stream>>>(part, cnt, bias, out);
}

// Round 8
// 239.513 us; speedup vs baseline: 1.1705x; 1.0050x over previous
//
#include <hip/hip_runtime.h>

// N=1024, F_NODE=64, F_EDGE=32, F_IN=160.
// out[a,j] = sum_b gated(a,b,j);  gated = relu(Hp)*sigmoid(Ha)
// Hp[a,b,j] = A[a,b]*(H[a]·W[0:64,j] + H[b]·W[64:128,j] + E[a,b]·W[128:160,j]) + bias[j]
// A in {0,1}: A=0 pairs contribute g0[j]=relu(bias)*sigmoid(bias) (constant).
// R8: compact is now ORDER-PRESERVING (ballot-free shuffle scan, no atomics)
// so idxg[a][.] is sorted ascending -> mga_main's E gather walks DRAM
// monotonically at ~50% density (page-friendly) instead of R7's 32KB-stride
// interleave (atomics scattered each thread's b, b+256, b+512, b+768
// contiguously -> random-line HBM gather, ~2-3 TB/s effective).
// mga_main itself is R7's passing structure, unchanged except comments.
#define NN 1024
#define FN 64
#define FE 32
#define FIN 160
#define NS 2            // splits of the compacted list per row

typedef __bf16 bf16x8 __attribute__((ext_vector_type(8)));
typedef short  short8 __attribute__((ext_vector_type(8)));
typedef float  f32x4  __attribute__((ext_vector_type(4)));

static __device__ __forceinline__ unsigned short f2b(float x){
    unsigned int u = __float_as_uint(x);
    unsigned int r = (u + 0x7fffu + ((u >> 16) & 1u)) >> 16;
    return (unsigned short)r;
}

static __device__ __forceinline__ float fast_sigmoid(float y){
    return __builtin_amdgcn_rcpf(1.0f + __expf(-y));
}

static __device__ __forceinline__ bf16x8 ldfrag(const unsigned short* p){
    return __builtin_bit_cast(bf16x8, *(const short8*)(p));
}

// pack two f32 -> (bf16 lo, bf16 hi) by truncation: one v_perm_b32
static __device__ __forceinline__ unsigned packtrunc(float lo, float hi){
    return __builtin_amdgcn_perm(__float_as_uint(hi), __float_as_uint(lo), 0x07060302u);
}

// blocks 0..63: H f32 -> Hb bf16 (1024x64); block 64/65: W/Wa -> Wt[j][k] bf16
__global__ void prep(const float* __restrict__ H, const float* __restrict__ W,
                     const float* __restrict__ Wa,
                     unsigned short* __restrict__ Hb,
                     unsigned short* __restrict__ WtE,
                     unsigned short* __restrict__ WtA){
    int bid = blockIdx.x, tid = threadIdx.x;
    if (bid < 64){
        int i = (bid*256 + tid)*4;
        float4 v = *(const float4*)(H + i);
        ushort4 o;
        o.x = f2b(v.x); o.y = f2b(v.y); o.z = f2b(v.z); o.w = f2b(v.w);
        *(ushort4*)(Hb + i) = o;
    } else {
        const float* src = (bid == 64) ? W : Wa;
        unsigned short* dst = (bid == 64) ? WtE : WtA;
        for (int idx = tid; idx < FIN*FN; idx += 256){
            int k = idx >> 6, j = idx & 63;
            dst[j*FIN + k] = f2b(src[idx]);
        }
    }
}

// Per row a: compact b with A[a,b]!=0 into idxg[a][.], SORTED ASCENDING.
// Lane owns 4 consecutive b; position via 64-lane shuffle inclusive scan
// + tiny cross-wave LDS scan. No atomics (R7's 256-way LDS-atomic serialize),
// order preserved (DRAM locality for the downstream gather).
__global__ void compact(const float* __restrict__ A, unsigned short* __restrict__ idxg,
                        int* __restrict__ cnt){
    int a = blockIdx.x, tid = threadIdx.x;
    int wave = tid >> 6, lane = tid & 63;
    int b0 = wave*256 + lane*4;
    float4 v = *(const float4*)(A + (size_t)a*NN + b0);
    unsigned short loc[4]; int m = 0;
    if (v.x != 0.f) loc[m++] = (unsigned short)(b0);
    if (v.y != 0.f) loc[m++] = (unsigned short)(b0 + 1);
    if (v.z != 0.f) loc[m++] = (unsigned short)(b0 + 2);
    if (v.w != 0.f) loc[m++] = (unsigned short)(b0 + 3);
    // inclusive scan of m across 64 lanes
    int sc = m;
    #pragma unroll
    for (int d = 1; d < 64; d <<= 1){
        int t = __shfl_up(sc, d, 64);
        sc += (lane >= d) ? t : 0;
    }
    __shared__ int wsum[4];
    if (lane == 63) wsum[wave] = sc;
    __syncthreads();
    int base = 0;
    #pragma unroll
    for (int w = 0; w < 4; w++) base += (w < wave) ? wsum[w] : 0;
    int pos = base + sc - m;
    for (int i = 0; i < m; i++) idxg[(size_t)a*NN + pos + i] = loc[i];
    if (tid == 0) cnt[a] = wsum[0] + wsum[1] + wsum[2] + wsum[3];
}

// Grid 2048: bid = a*NS + s; block processes its half of row a's sorted
// compacted list, 128 rows (2 sub-chunks) per iteration, loads batched.
// 4 waves, wave=(half<<1)|mh: half -> j-tiles {2half,2half+1}, mh -> 32-row
// half of each 64-row sub-chunk.
// mfma_f32_16x16x32_bf16: A[m=lane&15][k=quad*8+i], B[k][n=lane&15],
// D: col=lane&15, row=quad*4+reg  [measured m89/m91].
__global__ __launch_bounds__(256, 3) void mga_main(
    const float* __restrict__ E,
    const unsigned short* __restrict__ Hb,
    const unsigned short* __restrict__ WtE, const unsigned short* __restrict__ WtA,
    const unsigned short* __restrict__ idxg, const int* __restrict__ cnt,
    const float* __restrict__ bias, float* __restrict__ part)
{
    int bid  = blockIdx.x;
    int a    = bid >> 1, s = bid & 1;
    int tid  = threadIdx.x;
    int wave = tid >> 6, lane = tid & 63;
    int col  = lane & 15, quad = lane >> 4;
    int half = wave >> 1, mh = wave & 1;

    __shared__ unsigned short lidx[512];   // this block's (padded) index window
    __shared__ float red[16*FN];

    int c1   = cnt[a];
    int hlen = (c1 + 1) >> 1;
    int win  = s ? hlen : 0;
    int len  = s ? (c1 - hlen) : hlen;
    int npad = (len + 63) & ~63;

    for (int i = tid; i < npad; i += 256){
        int off = (i < len) ? i : (len - 1);
        lidx[i] = idxg[(size_t)a*NN + win + off];
    }

    // Held B-frags: k-segs {64..96,96..128,128..160} x 2 j-tiles x 2 mats
    bf16x8 Bw[2][3], Ba[2][3];
    #pragma unroll
    for (int tl = 0; tl < 2; tl++){
        int n = (2*half + tl)*16 + col;
        #pragma unroll
        for (int sg = 0; sg < 3; sg++){
            Bw[tl][sg] = ldfrag(WtE + n*FIN + (sg+2)*32 + quad*8);
            Ba[tl][sg] = ldfrag(WtA + n*FIN + (sg+2)*32 + quad*8);
        }
    }

    // Upfront c-init = bias[j] + H[a]·W[0:64,j] via broadcast-A MFMAs
    bf16x8 ha0 = ldfrag(Hb + a*FN + quad*8);
    bf16x8 ha1 = ldfrag(Hb + a*FN + 32 + quad*8);
    f32x4 cw[2], ca[2];
    float acc[2] = {0.f, 0.f};
    #pragma unroll
    for (int tl = 0; tl < 2; tl++){
        int n = (2*half + tl)*16 + col;
        float bj = bias[n];
        f32x4 cb = {bj, bj, bj, bj};
        bf16x8 b0 = ldfrag(WtE + n*FIN + quad*8);
        bf16x8 b1 = ldfrag(WtE + n*FIN + 32 + quad*8);
        cw[tl] = __builtin_amdgcn_mfma_f32_16x16x32_bf16(ha1, b1,
                 __builtin_amdgcn_mfma_f32_16x16x32_bf16(ha0, b0, cb, 0,0,0), 0,0,0);
        b0 = ldfrag(WtA + n*FIN + quad*8);
        b1 = ldfrag(WtA + n*FIN + 32 + quad*8);
        ca[tl] = __builtin_amdgcn_mfma_f32_16x16x32_bf16(ha1, b1,
                 __builtin_amdgcn_mfma_f32_16x16x32_bf16(ha0, b0, cb, 0,0,0), 0,0,0);
    }

    __syncthreads();   // lidx visible

    // In-flight data for 2 sub-chunks x 2 m-tiles (per-lane register path)
    float4 e0[2][2], e1[2][2]; bf16x8 h0[2][2], h1[2][2];

    auto loadsub = [&](int p, int sub){
        #pragma unroll
        for (int mt = 0; mt < 2; mt++){
            int r = lidx[p + mh*32 + mt*16 + col] & (NN - 1);
            const float* ep = E + ((size_t)a*NN + r)*FE + quad*8;
            e0[sub][mt] = *(const float4*)(ep);
            e1[sub][mt] = *(const float4*)(ep + 4);
            h0[sub][mt] = ldfrag(Hb + r*FN + quad*8);
            h1[sub][mt] = ldfrag(Hb + r*FN + 32 + quad*8);
        }
    };

    auto compsub = [&](int p, int sub){
        bool full = (p + 64) <= len;
        #pragma unroll
        for (int mt = 0; mt < 2; mt++){
            int4 pk;
            pk.x = (int)packtrunc(e0[sub][mt].x, e0[sub][mt].y);
            pk.y = (int)packtrunc(e0[sub][mt].z, e0[sub][mt].w);
            pk.z = (int)packtrunc(e1[sub][mt].x, e1[sub][mt].y);
            pk.w = (int)packtrunc(e1[sub][mt].z, e1[sub][mt].w);
            bf16x8 ef = __builtin_bit_cast(bf16x8, pk);
            #pragma unroll
            for (int tl = 0; tl < 2; tl++){
                f32x4 pw = __builtin_amdgcn_mfma_f32_16x16x32_bf16(ef, Bw[tl][2],
                           __builtin_amdgcn_mfma_f32_16x16x32_bf16(h1[sub][mt], Bw[tl][1],
                           __builtin_amdgcn_mfma_f32_16x16x32_bf16(h0[sub][mt], Bw[tl][0],
                               cw[tl], 0,0,0), 0,0,0), 0,0,0);
                f32x4 pa = __builtin_amdgcn_mfma_f32_16x16x32_bf16(ef, Ba[tl][2],
                           __builtin_amdgcn_mfma_f32_16x16x32_bf16(h1[sub][mt], Ba[tl][1],
                           __builtin_amdgcn_mfma_f32_16x16x32_bf16(h0[sub][mt], Ba[tl][0],
                               ca[tl], 0,0,0), 0,0,0), 0,0,0);
                if (full){
                    #pragma unroll
                    for (int r = 0; r < 4; r++)
                        acc[tl] += fmaxf(pw[r], 0.f) * fast_sigmoid(pa[r]);
                } else {
                    #pragma unroll
                    for (int r = 0; r < 4; r++){
                        int pos = p + mh*32 + mt*16 + quad*4 + r;
                        float f = fmaxf(pw[r], 0.f) * fast_sigmoid(pa[r]);
                        acc[tl] += (pos < len) ? f : 0.f;
                    }
                }
            }
        }
    };

    for (int p = 0; p < npad; p += 128){
        bool hasB = (p + 64) < npad;          // uniform per block
        loadsub(p, 0);
        if (hasB) loadsub(p + 64, 1);         // 16 independent loads in flight
        compsub(p, 0);
        if (hasB) compsub(p + 64, 1);
    }

    #pragma unroll
    for (int tl = 0; tl < 2; tl++)
        red[(wave*4 + quad)*FN + (2*half + tl)*16 + col] = acc[tl];
    __syncthreads();
    if (tid < FN){
        int base = (tid >= 32) ? 8 : 0;   // waves 0,1: j<32; waves 2,3: j>=32
        float sum = 0.f;
        #pragma unroll
        for (int r = 0; r < 8; r++) sum += red[(base + r)*FN + tid];
        part[((size_t)s*NN + a)*FN + tid] = sum;
    }
}

// out[a,j] = part0 + part1 + (N - cnt1[a]) * g0[j]
__global__ void mga_reduce(const float* __restrict__ part, const int* __restrict__ cnt,
                           const float* __restrict__ bias, float* __restrict__ out){
    int i = blockIdx.x*256 + threadIdx.x;   // 0..65535
    int a = i >> 6, j = i & 63;
    float bj = bias[j];
    float g0 = fmaxf(bj, 0.f) * fast_sigmoid(bj);
    float c0 = (float)(NN - cnt[a]);
    out[i] = part[i] + part[(size_t)NN*FN + i] + c0 * g0;
}

extern "C" void kernel_launch(void* const* d_in, const int* in_sizes, int n_in,
                              void* d_out, int out_size, void* d_ws, size_t ws_size,
                              hipStream_t stream) {
    const float* H    = (const float*)d_in[0];
    const float* A    = (const float*)d_in[1];
    const float* E    = (const float*)d_in[2];
    const float* W    = (const float*)d_in[3];
    const float* Wa   = (const float*)d_in[4];
    const float* bias = (const float*)d_in[5];
    float* out = (float*)d_out;

    unsigned short* Hb   = (unsigned short*)d_ws;         // 1024*64 bf16
    unsigned short* WtE  = Hb + NN*FN;                    // 64*160
    unsigned short* WtA  = WtE + FN*FIN;                  // 64*160
    unsigned short* idxg = WtA + FN*FIN;                  // 1024*1024 u16 (2 MB)
    int*            cnt  = (int*)(idxg + (size_t)NN*NN);  // 1024
    float*          part = (float*)(cnt + NN);            // NS*1024*64 f32

    prep      <<<dim3(66),    dim3(256), 0, stream>>>(H, W, Wa, Hb, WtE, WtA);
    compact   <<<dim3(NN),    dim3(256), 0, stream>>>(A, idxg, cnt);
    mga_main  <<<dim3(NN*NS), dim3(256), 0, stream>>>(E, Hb, WtE, WtA, idxg, cnt, bias, part);
    mga_reduce<<<dim3(256),   dim3(256), 0, stream>>>(part, cnt, bias, out);
}